// Round 11
// baseline (834.483 us; speedup 1.0000x reference)
//
#include <hip/hip_runtime.h>

typedef _Float16 f16;
typedef _Float16 f16x8 __attribute__((ext_vector_type(8)));
typedef _Float16 f16x4 __attribute__((ext_vector_type(4)));
typedef float    f32x16 __attribute__((ext_vector_type(16)));

#define GLDS(gp, lp) __builtin_amdgcn_global_load_lds( \
    (const __attribute__((address_space(1))) void*)(gp), \
    (__attribute__((address_space(3))) void*)(lp), 16, 0, 0)

// ---------------------------------------------------------------------------
// 256x256 tile, BK=64, 512 threads (8 waves 2x4, 128x64 per wave), 8-phase
// K-loop with counted vmcnt(6) prefetch, LDS XOR-swizzle, s_setprio around
// MFMA clusters.  Double-buffered 128 KiB LDS.  (Proven R5/R7 form; 808 TF
// measured on the G1 shape.)
// TROUT: additionally emit the transposed output Ct[b][col][row] (f16),
// b = row/2048 — used by G1 to produce tQt in-epilogue, replacing the
// standalone transpose kernel.  The K-loop LDS buffers (As+Bs = 128 KiB =
// one 256x256 f16 tile) are dead after the final phase barrier and are
// reused as the transpose scratch.
// ---------------------------------------------------------------------------
template<typename OUT_T, bool BIAS, bool RELU, bool TROUT>
__global__ __launch_bounds__(512, 2)
void gemm_bt2(const f16* __restrict__ A, const f16* __restrict__ Bm,
              OUT_T* __restrict__ C, const float* __restrict__ bias,
              int M, int N, int K, long sA, long sB, long sC,
              f16* __restrict__ Ct)
{
    constexpr int TSZ = 256 * 64;          // f16 elements per tile buffer
    __shared__ alignas(16) f16 As[2 * TSZ];
    __shared__ alignas(16) f16 Bs[2 * TSZ];

    int bx = blockIdx.x, by = blockIdx.y;
    {   // XCD-locality remap (gy % 8 == 0 for all uses)
        const int gx = gridDim.x;
        const int l = by * gx + bx;
        const int W = gx * 8;
        const int ygrp = l / W;
        const int rem = l - ygrp * W;
        bx = rem >> 3;
        by = ygrp * 8 + (rem & 7);
    }
    const int z = blockIdx.z;
    A  += (long)z * sA;
    Bm += (long)z * sB;
    C  += (long)z * sC;

    const int tid  = threadIdx.x;
    const int wid  = tid >> 6;
    const int lane = tid & 63;
    const int lr = lane & 31;
    const int lh = lane >> 5;
    const int m0 = by * 256;
    const int n0 = bx * 256;
    const int wm = (wid >> 2) * 128;       // wave row: 0 or 128
    const int wn = (wid & 3) * 64;         // wave col: 0,64,128,192

    // staging: one GLDS call covers 64 rows (8 rows/wave, 8 x 16B slots/row).
    // LDS row r slot s holds source k-segment (s ^ (r&7))  [XOR swizzle]
    const int sr = tid >> 3;                         // row within 64-row call
    const int sg = ((tid & 7) ^ (sr & 7)) * 8;       // pre-swizzled source col
    const f16* agS = A  + (long)(m0 + sr) * K + sg;
    const f16* bgS = Bm + (long)(n0 + sr) * K + sg;
    f16* aD = As + wid * (8 * 64);                   // wave-uniform LDS base
    f16* bD = Bs + wid * (8 * 64);

    // fragment read: k-segment g = 2*ks + lh at slot g ^ (row&7)
    const int s7  = lr & 7;
    const int xs0 = ((0 + lh) ^ s7) * 8;
    const int xs1 = ((2 + lh) ^ s7) * 8;
    const int xs2 = ((4 + lh) ^ s7) * 8;
    const int xs3 = ((6 + lh) ^ s7) * 8;
    const f16* aR = As + (wm + lr) * 64;
    const f16* bR = Bs + (wn + lr) * 64;

    f32x16 acc[4][2];
#pragma unroll
    for (int mi = 0; mi < 4; ++mi)
#pragma unroll
        for (int ni = 0; ni < 2; ++ni)
#pragma unroll
            for (int r = 0; r < 16; ++r) acc[mi][ni][r] = 0.f;

    f16x8 b00, b01, b02, b03, b10, b11, b12, b13;

    const int NT = K >> 6;

#define GAc(buf, R0, kt) GLDS(agS + (long)(R0) * K + (kt), aD + (buf) * TSZ + (R0) * 64)
#define GBc(buf, R0, kt) GLDS(bgS + (long)(R0) * K + (kt), bD + (buf) * TSZ + (R0) * 64)

    // prologue: tile0 -> buf0 (B then A = oldest 8), tile1 -> buf1 (B all, A head)
    GBc(0,   0, 0);  GBc(0,  64, 0);  GBc(0, 128, 0);  GBc(0, 192, 0);
    GAc(0,   0, 0);  GAc(0,  64, 0);  GAc(0, 128, 0);  GAc(0, 192, 0);
    GBc(1,   0, 64); GBc(1,  64, 64); GBc(1, 128, 64); GBc(1, 192, 64);
    GAc(1,   0, 64); GAc(1, 128, 64);
    asm volatile("s_waitcnt vmcnt(6)" ::: "memory");   // buf0 fully landed
    __builtin_amdgcn_s_barrier();

#define MFMA8(mi) \
    acc[mi][0] = __builtin_amdgcn_mfma_f32_32x32x16_f16(af0, b00, acc[mi][0], 0, 0, 0); \
    acc[mi][1] = __builtin_amdgcn_mfma_f32_32x32x16_f16(af0, b10, acc[mi][1], 0, 0, 0); \
    acc[mi][0] = __builtin_amdgcn_mfma_f32_32x32x16_f16(af1, b01, acc[mi][0], 0, 0, 0); \
    acc[mi][1] = __builtin_amdgcn_mfma_f32_32x32x16_f16(af1, b11, acc[mi][1], 0, 0, 0); \
    acc[mi][0] = __builtin_amdgcn_mfma_f32_32x32x16_f16(af2, b02, acc[mi][0], 0, 0, 0); \
    acc[mi][1] = __builtin_amdgcn_mfma_f32_32x32x16_f16(af2, b12, acc[mi][1], 0, 0, 0); \
    acc[mi][0] = __builtin_amdgcn_mfma_f32_32x32x16_f16(af3, b03, acc[mi][0], 0, 0, 0); \
    acc[mi][1] = __builtin_amdgcn_mfma_f32_32x32x16_f16(af3, b13, acc[mi][1], 0, 0, 0);

// Phase: frag ds_reads | GLDS issues | barrier | 8 MFMA (compiler inserts
// progressive lgkmcnt per frag dependency) | [vmcnt gate] | barrier
#define PH(buf, mi, VW, ...) { \
    f16x8 af0 = *(const f16x8*)(aR + (buf) * TSZ + (mi) * 2048 + xs0); \
    f16x8 af1 = *(const f16x8*)(aR + (buf) * TSZ + (mi) * 2048 + xs1); \
    f16x8 af2 = *(const f16x8*)(aR + (buf) * TSZ + (mi) * 2048 + xs2); \
    f16x8 af3 = *(const f16x8*)(aR + (buf) * TSZ + (mi) * 2048 + xs3); \
    if ((mi) == 0) { \
        b00 = *(const f16x8*)(bR + (buf) * TSZ + xs0); \
        b01 = *(const f16x8*)(bR + (buf) * TSZ + xs1); \
        b02 = *(const f16x8*)(bR + (buf) * TSZ + xs2); \
        b03 = *(const f16x8*)(bR + (buf) * TSZ + xs3); \
        b10 = *(const f16x8*)(bR + (buf) * TSZ + 2048 + xs0); \
        b11 = *(const f16x8*)(bR + (buf) * TSZ + 2048 + xs1); \
        b12 = *(const f16x8*)(bR + (buf) * TSZ + 2048 + xs2); \
        b13 = *(const f16x8*)(bR + (buf) * TSZ + 2048 + xs3); \
    } \
    __VA_ARGS__ \
    __builtin_amdgcn_s_barrier(); \
    __builtin_amdgcn_s_setprio(1); \
    MFMA8(mi) \
    __builtin_amdgcn_s_setprio(0); \
    if (VW) { asm volatile("s_waitcnt vmcnt(6)" ::: "memory"); } \
    __builtin_amdgcn_s_barrier(); \
}

    for (int i = 0; i < NT / 2; ++i) {
        const long k1 = (long)(2 * i + 1) << 6;                           // tile t+1 (tail)
        const long kA = (2 * i + 2 < NT) ? ((long)(2 * i + 2) << 6) : 0;  // tile t+2
        const long kB = (2 * i + 3 < NT) ? ((long)(2 * i + 3) << 6) : 0;  // tile t+3
        PH(0, 0, 0, GAc(1,  64, k1); GAc(1, 192, k1);)
        PH(0, 1, 0, GBc(0,   0, kA); GBc(0,  64, kA);)
        PH(0, 2, 0, GBc(0, 128, kA); GBc(0, 192, kA);)
        PH(0, 3, 1, GAc(0,   0, kA); GAc(0, 128, kA);)
        PH(1, 0, 0, GAc(0,  64, kA); GAc(0, 192, kA);)
        PH(1, 1, 0, GBc(1,   0, kB); GBc(1,  64, kB);)
        PH(1, 2, 0, GBc(1, 128, kB); GBc(1, 192, kB);)
        PH(1, 3, 1, GAc(1,   0, kB); GAc(1, 128, kB);)
    }

    asm volatile("s_waitcnt vmcnt(0)" ::: "memory");    // drain before LDS reuse

    // C/D layout (32x32): col = lane&31, row = (reg&3) + 8*(reg>>2) + 4*(lane>>5)
#pragma unroll
    for (int ni = 0; ni < 2; ++ni) {
        const int gc = n0 + wn + ni * 32 + lr;
        const float bv = BIAS ? bias[gc] : 0.0f;
#pragma unroll
        for (int mi = 0; mi < 4; ++mi) {
#pragma unroll
            for (int r = 0; r < 16; ++r) {
                const int row = (r & 3) + 8 * (r >> 2) + 4 * lh;
                const int gr = m0 + wm + mi * 32 + row;
                float v = acc[mi][ni][r] + bv;
                if (RELU) v = fmaxf(v, 0.0f);
                C[(long)gr * N + gc] = (OUT_T)v;
            }
        }
    }

    if constexpr (TROUT) {
        // Transposed output: Ct[b][col][row], b = global_row/2048.
        // K-loop LDS is dead (last phase ended with s_barrier after all
        // ds_reads were consumed).  Layout: cols 0-127 -> As, 128-255 -> Bs,
        // each [128 cols][256 rows] f16 (exactly 64 KiB).  Bank spread via
        // byte ^= (col&15)<<3 on 8B-aligned chunks (write ~4-way, read ~4-way).
        // NOTE: values bit-identical to C (same (f16)(acc+bias) conversion).
#pragma unroll
        for (int ni = 0; ni < 2; ++ni) {
            const int c  = wn + ni * 32 + lr;          // 0..255, unique/thread
            f16* T = (c & 128) ? Bs : As;
            const int cl = c & 127;
            const float bv = BIAS ? bias[n0 + c] : 0.0f;
#pragma unroll
            for (int mi = 0; mi < 4; ++mi) {
#pragma unroll
                for (int g = 0; g < 4; ++g) {
                    const int rbase = wm + mi * 32 + 8 * g + 4 * lh;  // mult of 4
                    float v0 = acc[mi][ni][4 * g + 0] + bv;
                    float v1 = acc[mi][ni][4 * g + 1] + bv;
                    float v2 = acc[mi][ni][4 * g + 2] + bv;
                    float v3 = acc[mi][ni][4 * g + 3] + bv;
                    if (RELU) {
                        v0 = fmaxf(v0, 0.f); v1 = fmaxf(v1, 0.f);
                        v2 = fmaxf(v2, 0.f); v3 = fmaxf(v3, 0.f);
                    }
                    f16x4 hv = {(f16)v0, (f16)v1, (f16)v2, (f16)v3};
                    const int byte = ((cl * 256 + rbase) * 2) ^ ((cl & 15) << 3);
                    *(f16x4*)((char*)T + byte) = hv;
                }
            }
        }
        __builtin_amdgcn_s_barrier();
        // read + store: thread -> (col = tid>>2, rowseg = (tid&3)*64), both halves
        const int tcol = tid >> 2;          // 0..127
        const int rseg = (tid & 3) * 64;    // 0,64,128,192
        const long bq  = (long)(m0 >> 11) * ((long)N * 2048) + (m0 & 2047) + rseg;
#pragma unroll
        for (int half = 0; half < 2; ++half) {
            f16* T = half ? Bs : As;
            f16* dst = Ct + bq + (long)(n0 + half * 128 + tcol) * 2048;
#pragma unroll
            for (int j = 0; j < 16; ++j) {
                const int byte = ((tcol * 256 + rseg + 4 * j) * 2) ^ ((tcol & 15) << 3);
                *(f16x4*)(dst + 4 * j) = *(const f16x4*)((const char*)T + byte);
            }
        }
    }
#undef PH
#undef MFMA8
#undef GAc
#undef GBc
}

// ---------------------------------------------------------------------------
// Fused cast: proj_p -> pB (blocks [0,16384)), proj_q -> qB ([16384,32768)),
// W -> Wb ([32768, 33280)).  One launch instead of three.
__global__ __launch_bounds__(256)
void cast_all(const float* __restrict__ Xp, const float* __restrict__ Xq,
              const float* __restrict__ Xw, f16* __restrict__ Yp,
              f16* __restrict__ Yq, f16* __restrict__ Yw)
{
    const long b = blockIdx.x;
    const float* X;
    f16* Y;
    long off;
    if (b < 16384)      { X = Xp; Y = Yp; off = b; }
    else if (b < 32768) { X = Xq; Y = Yq; off = b - 16384; }
    else                { X = Xw; Y = Yw; off = b - 32768; }
    const long i = (off * 256 + threadIdx.x) * 8;
    float4 a = *(const float4*)(X + i);
    float4 c = *(const float4*)(X + i + 4);
    f16x8 h = {(f16)a.x, (f16)a.y, (f16)a.z, (f16)a.w,
               (f16)c.x, (f16)c.y, (f16)c.z, (f16)c.w};
    *(f16x8*)(Y + i) = h;
}

// rowwise softmax over 2048 f16 scores -> fp16 probabilities
__global__ __launch_bounds__(256)
void softmax_ph(const f16* __restrict__ S, f16* __restrict__ P)
{
    const long row = blockIdx.x;
    const f16* s = S + row * 2048;
    f16* p = P + row * 2048;
    const int tid = threadIdx.x;
    const int wid = tid >> 6, lane = tid & 63;

    f16x8 hv = *(const f16x8*)(s + tid * 8);
    float v[8] = {(float)hv[0], (float)hv[1], (float)hv[2], (float)hv[3],
                  (float)hv[4], (float)hv[5], (float)hv[6], (float)hv[7]};

    float m = v[0];
#pragma unroll
    for (int j = 1; j < 8; ++j) m = fmaxf(m, v[j]);
#pragma unroll
    for (int off = 32; off > 0; off >>= 1) m = fmaxf(m, __shfl_xor(m, off, 64));

    __shared__ float red[8];
    if (lane == 0) red[wid] = m;
    __syncthreads();
    m = fmaxf(fmaxf(red[0], red[1]), fmaxf(red[2], red[3]));

    float sum = 0.f;
#pragma unroll
    for (int j = 0; j < 8; ++j) { v[j] = __expf(v[j] - m); sum += v[j]; }
#pragma unroll
    for (int off = 32; off > 0; off >>= 1) sum += __shfl_xor(sum, off, 64);
    if (lane == 0) red[4 + wid] = sum;
    __syncthreads();
    sum = red[4] + red[5] + red[6] + red[7];

    const float inv = 1.0f / sum;
    f16x8 h = {(f16)(v[0] * inv), (f16)(v[1] * inv), (f16)(v[2] * inv), (f16)(v[3] * inv),
               (f16)(v[4] * inv), (f16)(v[5] * inv), (f16)(v[6] * inv), (f16)(v[7] * inv)};
    *(f16x8*)(p + tid * 8) = h;
}

// ---------------------------------------------------------------------------
extern "C" void kernel_launch(void* const* d_in, const int* in_sizes, int n_in,
                              void* d_out, int out_size, void* d_ws, size_t ws_size,
                              hipStream_t stream)
{
    const float* proj_p = (const float*)d_in[0];  // [16,2048,1024]
    const float* proj_q = (const float*)d_in[1];  // [16,2048,1024]
    const float* W      = (const float*)d_in[2];  // [1024,1024]
    const float* bias   = (const float*)d_in[3];  // [1024]
    float* out = (float*)d_out;

    constexpr long Bc = 16, L = 2048, H = 1024;

    // Workspace layout (single-chunk, z=16 everywhere).  Liveness overlay:
    //   P (128 MB) overlays pB+qB — pB dead after G2, qB dead after G1,
    //   softmax (the writer of P) runs strictly after G2 on this stream.
    char* ws = (char*)d_ws;
    f16*   pB  = (f16*)(ws + 0L);                 // 67,108,864 B
    f16*   qB  = (f16*)(ws + 67108864L);          // 67,108,864 B
    f16*   tQ  = (f16*)(ws + 134217728L);         // 67,108,864 B  [B*L][H]
    f16*   tQt = (f16*)(ws + 201326592L);         // 67,108,864 B  [B][H][L]
    f16*   Wb  = (f16*)(ws + 268435456L);         //  2,097,152 B
    f16*   Sh  = (f16*)(ws + 270532608L);         // 134,217,728 B (16 batches f16)
    f16*   P   = (f16*)(ws + 0L);                 // 134,217,728 B (overlay pB+qB)

    // 1. all input casts in one launch
    cast_all<<<33280, 256, 0, stream>>>(proj_p, proj_q, W, pB, qB, Wb);

    // 2. G1: tQ[b,q,o] = qB[b,q,:] . Wb[o,:] + bias[o]   (256-tile 8-phase)
    //    TROUT=true also emits tQt[b][o][q] from the epilogue (replaces the
    //    standalone transpose kernel: saves its 67 MB read + launch).
    gemm_bt2<f16, true, false, true><<<dim3(H / 256, (Bc * L) / 256, 1), 512, 0, stream>>>(
        qB, Wb, tQ, bias, (int)(Bc * L), (int)H, (int)H, 0, 0, 0, tQt);

    // 3. G2: Sh[b][p,q] = pB[b][p,:] . tQ[b][q,:]   (f16 out, all 16 batches)
    gemm_bt2<f16, false, false, false><<<dim3(L / 256, L / 256, (int)Bc), 512, 0, stream>>>(
        pB, tQ, Sh, nullptr, (int)L, (int)L, (int)H, L * H, L * H, L * L, nullptr);

    // 4. softmax rows (f16 in) -> P f16   (P overlays pB/qB — both dead now)
    softmax_ph<<<(int)(Bc * L), 256, 0, stream>>>(Sh, P);

    // 5. G3': out[b][p,o] = relu( P[b][p,:] . tQt[b][o,:] )
    gemm_bt2<float, false, true, false><<<dim3(H / 256, L / 256, (int)Bc), 512, 0, stream>>>(
        P, tQt, out, nullptr, (int)L, (int)H, (int)L, L * L, H * L, L * H, nullptr);
}